// Round 2
// baseline (703.819 us; speedup 1.0000x reference)
//
#include <hip/hip_runtime.h>
#include <hip/hip_bf16.h>
#include <stdint.h>

typedef unsigned short u16;
typedef __attribute__((ext_vector_type(8))) short s16x8;
typedef __attribute__((ext_vector_type(4))) float f32x4;

#define B_ 2
#define S_ 2048
#define H_ 2304
#define NH_ 8
#define NKV_ 4
#define HD_ 256

__device__ __forceinline__ float bf2f(u16 u) {
  union { uint32_t i; float f; } x; x.i = ((uint32_t)u) << 16; return x.f;
}
__device__ __forceinline__ u16 f2bf(float f) {
  union { float f; uint32_t i; } x; x.f = f;
  uint32_t u = x.i;
  return (u16)((u + 0x7fffu + ((u >> 16) & 1u)) >> 16);
}

__device__ __forceinline__ void async16(const void* g, void* l) {
  __builtin_amdgcn_global_load_lds((const __attribute__((address_space(1))) uint32_t*)g,
                                   (__attribute__((address_space(3))) uint32_t*)l, 16, 0, 0);
}

__device__ __forceinline__ f32x4 mfma16(s16x8 a, s16x8 b, f32x4 c) {
  return __builtin_amdgcn_mfma_f32_16x16x32_bf16(a, b, c, 0, 0, 0);
}

// ---------------- fp32 -> bf16 elementwise convert ----------------
__global__ void f32_to_bf16(const float* __restrict__ in, u16* __restrict__ out, size_t n) {
  size_t i = ((size_t)blockIdx.x * blockDim.x + threadIdx.x) * 4;
  if (i + 3 < n) {
    float4 v = *(const float4*)(in + i);
    ushort4 o;
    o.x = f2bf(v.x); o.y = f2bf(v.y); o.z = f2bf(v.z); o.w = f2bf(v.w);
    *(ushort4*)(out + i) = o;
  }
}

// ---------------- transpose fp32 in -> bf16 out: in[R][C] -> out[C][R] ----------------
__global__ void transpose_f32_bf16(const float* __restrict__ in, u16* __restrict__ out, int R, int C) {
  __shared__ u16 tile[32][33];
  int c0 = blockIdx.x * 32, r0 = blockIdx.y * 32;
  int x = threadIdx.x, y = threadIdx.y;
#pragma unroll
  for (int j = 0; j < 32; j += 8)
    tile[y + j][x] = f2bf(in[(size_t)(r0 + y + j) * C + c0 + x]);
  __syncthreads();
#pragma unroll
  for (int j = 0; j < 32; j += 8)
    out[(size_t)(c0 + y + j) * R + r0 + x] = tile[x][y + j];
}

// ---------------- transpose bf16 -> bf16 (batched along z) ----------------
__global__ void transpose_bf16(const u16* __restrict__ in, u16* __restrict__ out, int R, int C) {
  __shared__ u16 tile[32][33];
  size_t bofs = (size_t)blockIdx.z * R * C;
  in += bofs; out += bofs;
  int c0 = blockIdx.x * 32, r0 = blockIdx.y * 32;
  int x = threadIdx.x, y = threadIdx.y;
#pragma unroll
  for (int j = 0; j < 32; j += 8)
    tile[y + j][x] = in[(size_t)(r0 + y + j) * C + c0 + x];
  __syncthreads();
#pragma unroll
  for (int j = 0; j < 32; j += 8)
    out[(size_t)(c0 + y + j) * R + r0 + x] = tile[x][y + j];
}

// ---------------- GEMM: C[M][N] = A[M][Kd] * BT[N][Kd]^T (bf16 in, bf16 or f32 out) ----
template <bool F32OUT>
__global__ __launch_bounds__(256) void gemm_bt(const u16* __restrict__ A, const u16* __restrict__ BT,
                                               void* __restrict__ Cout, int M, int N, int Kd) {
  __shared__ u16 As[128 * 32];
  __shared__ u16 Bs[128 * 32];
  int tid = threadIdx.x;
  int lane = tid & 63, wave = tid >> 6;
  int bm = blockIdx.y * 128, bn = blockIdx.x * 128;
  int wm = (wave >> 1) * 64, wn = (wave & 1) * 64;
  int fr = lane & 15, fq = lane >> 4;
  f32x4 zero4 = {0.f, 0.f, 0.f, 0.f};
  f32x4 acc[4][4];
#pragma unroll
  for (int i = 0; i < 4; i++)
#pragma unroll
    for (int j = 0; j < 4; j++) acc[i][j] = zero4;

  int arow = tid >> 2, aoff = (tid & 3) * 8;
  const u16* Ab = A + (size_t)(bm + arow) * Kd + aoff;
  const u16* Bb = BT + (size_t)(bn + arow) * Kd + aoff;
  char* AsB = (char*)As + wave * 1024;
  char* BsB = (char*)Bs + wave * 1024;

  for (int k0 = 0; k0 < Kd; k0 += 32) {
    async16(Ab + k0, AsB);
    async16(Ab + (size_t)64 * Kd + k0, AsB + 4096);
    async16(Bb + k0, BsB);
    async16(Bb + (size_t)64 * Kd + k0, BsB + 4096);
    __syncthreads();
    s16x8 af[4], bv[4];
#pragma unroll
    for (int i = 0; i < 4; i++) af[i] = *(const s16x8*)&As[(wm + i * 16 + fr) * 32 + fq * 8];
#pragma unroll
    for (int j = 0; j < 4; j++) bv[j] = *(const s16x8*)&Bs[(wn + j * 16 + fr) * 32 + fq * 8];
#pragma unroll
    for (int i = 0; i < 4; i++)
#pragma unroll
      for (int j = 0; j < 4; j++)
        acc[i][j] = mfma16(af[i], bv[j], acc[i][j]);
    __syncthreads();
  }
#pragma unroll
  for (int i = 0; i < 4; i++)
#pragma unroll
    for (int j = 0; j < 4; j++)
#pragma unroll
      for (int r = 0; r < 4; r++) {
        int row = bm + wm + i * 16 + fq * 4 + r;
        int col = bn + wn + j * 16 + fr;
        if (F32OUT) ((float*)Cout)[(size_t)row * N + col] = acc[i][j][r];
        else        ((u16*)Cout)[(size_t)row * N + col] = f2bf(acc[i][j][r]);
      }
}

// ---------------- RoPE in-place (+optional scale), one thread per (row,head,pair) ----
__global__ void rope_kernel(u16* __restrict__ buf, const int* __restrict__ pos_ids,
                            int nheads, int rowlen, float scale) {
  int idx = blockIdx.x * blockDim.x + threadIdx.x;
  int d = idx & 127;
  int hn = idx >> 7;
  int h = hn % nheads;
  int row = hn / nheads;
  float pos = (float)pos_ids[row];
  double invf = exp((double)d * -0.07195578415606394); // -ln(10000)/128
  double f = (double)pos * invf;
  double sd, cd;
  sincos(f, &sd, &cd);
  float sv = (float)sd, cv = (float)cd;
  size_t base = (size_t)row * rowlen + (size_t)h * HD_ + d;
  float a = bf2f(buf[base]);
  float b = bf2f(buf[base + 128]);
  buf[base]       = f2bf((a * cv - b * sv) * scale);
  buf[base + 128] = f2bf((b * cv + a * sv) * scale);
}

// ---------------- flash attention with tanh softcap ----------------
// grid: (S/64, B*NH). block 256 = 4 waves x 16 q-rows. 64-key steps.
__global__ __launch_bounds__(256) void attn_kernel(const u16* __restrict__ Q, const u16* __restrict__ K,
                                                   const u16* __restrict__ VT, const int* __restrict__ amask,
                                                   u16* __restrict__ O) {
  __shared__ u16 Kl[64 * 256];     // [key][hd]  32 KiB
  __shared__ u16 Vl[256 * 64];     // [hd][key]  32 KiB
  __shared__ u16 Pl[4][16 * 64];   // per-wave P  8 KiB
  int qt = blockIdx.x, bh = blockIdx.y;
  int b = bh >> 3, h = bh & 7, g = h >> 1;
  int tid = threadIdx.x, lane = tid & 63, wave = tid >> 6;
  int fr = lane & 15, fq = lane >> 4;
  int q0 = qt * 64;

  // Q fragments in registers (Q already scaled by 1/16 in rope)
  s16x8 qf[8];
  const u16* qb = Q + (size_t)(b * S_ + q0 + wave * 16 + fr) * 2048 + h * 256 + fq * 8;
#pragma unroll
  for (int kk = 0; kk < 8; kk++) qf[kk] = *(const s16x8*)(qb + kk * 32);

  f32x4 zero4 = {0.f, 0.f, 0.f, 0.f};
  f32x4 oacc[16];
#pragma unroll
  for (int i = 0; i < 16; i++) oacc[i] = zero4;
  float m_run[4] = {-1e30f, -1e30f, -1e30f, -1e30f};
  float l_run[4] = {0.f, 0.f, 0.f, 0.f};

  const u16* Kbase = K + (size_t)b * S_ * 1024 + g * 256;
  const u16* Vbase = VT + (size_t)(b * 4 + g) * 256 * S_;
  int kr = tid >> 5, ko = (tid & 31) * 8;
  int vr = tid >> 3, vo = (tid & 7) * 8;
  char* KlB = (char*)Kl + wave * 1024;
  char* VlB = (char*)Vl + wave * 1024;

  for (int t = 0; t <= qt; ++t) {
    int k0 = t * 64;
#pragma unroll
    for (int it = 0; it < 8; ++it) {
      async16(Kbase + (size_t)(k0 + it * 8 + kr) * 1024 + ko, KlB + it * 4096);
      async16(Vbase + (size_t)(it * 32 + vr) * S_ + k0 + vo, VlB + it * 4096);
    }
    __syncthreads();

    f32x4 sacc[4];
#pragma unroll
    for (int n = 0; n < 4; n++) sacc[n] = zero4;
#pragma unroll
    for (int kk = 0; kk < 8; kk++) {
#pragma unroll
      for (int n = 0; n < 4; n++) {
        s16x8 bv = *(const s16x8*)&Kl[(n * 16 + fr) * 256 + kk * 32 + fq * 8];
        sacc[n] = mfma16(qf[kk], bv, sacc[n]);
      }
    }

    int diag = (t == qt);
    int am[4];
#pragma unroll
    for (int n = 0; n < 4; n++) am[n] = amask[b * S_ + k0 + n * 16 + fr];

#pragma unroll
    for (int r = 0; r < 4; r++) {
      int qg = q0 + wave * 16 + fq * 4 + r;
      float sv[4];
      float mx = -1e30f;
#pragma unroll
      for (int n = 0; n < 4; n++) {
        float s = 50.f * tanhf(sacc[n][r] * 0.02f);   // softcap
        int kg = k0 + n * 16 + fr;
        bool ok = (am[n] > 0) && (!diag || kg <= qg);
        sv[n] = ok ? s : -1e30f;
        mx = fmaxf(mx, sv[n]);
      }
#pragma unroll
      for (int off = 1; off < 16; off <<= 1) mx = fmaxf(mx, __shfl_xor(mx, off));
      float mnew = fmaxf(m_run[r], mx);
      float alpha = expf(m_run[r] - mnew);
      float lsum = 0.f;
#pragma unroll
      for (int n = 0; n < 4; n++) {
        float p = expf(sv[n] - mnew);
        lsum += p;
        Pl[wave][(fq * 4 + r) * 64 + n * 16 + fr] = f2bf(p);
      }
#pragma unroll
      for (int off = 1; off < 16; off <<= 1) lsum += __shfl_xor(lsum, off);
      m_run[r] = mnew;
      l_run[r] = l_run[r] * alpha + lsum;
#pragma unroll
      for (int df = 0; df < 16; df++) oacc[df][r] *= alpha;
    }
    asm volatile("s_waitcnt lgkmcnt(0)" ::: "memory");

#pragma unroll
    for (int kk = 0; kk < 2; kk++) {
      s16x8 pf = *(const s16x8*)&Pl[wave][fr * 64 + kk * 32 + fq * 8];
#pragma unroll
      for (int df = 0; df < 16; df++) {
        s16x8 vv = *(const s16x8*)&Vl[(df * 16 + fr) * 64 + kk * 32 + fq * 8];
        oacc[df] = mfma16(pf, vv, oacc[df]);
      }
    }
    __syncthreads();
  }

#pragma unroll
  for (int df = 0; df < 16; df++) {
#pragma unroll
    for (int r = 0; r < 4; r++) {
      float ov = oacc[df][r] / l_run[r];
      O[(size_t)(b * S_ + q0 + wave * 16 + fq * 4 + r) * 2048 + h * 256 + df * 16 + fr] = f2bf(ov);
    }
  }
}

extern "C" void kernel_launch(void* const* d_in, const int* in_sizes, int n_in,
                              void* d_out, int out_size, void* d_ws, size_t ws_size,
                              hipStream_t stream) {
  const float* X   = (const float*)d_in[0];   // [B,S,H] fp32
  const int* amask = (const int*)d_in[1];
  const int* pos   = (const int*)d_in[2];
  const float* Wq  = (const float*)d_in[3];   // [H, NH*HD] fp32
  const float* Wk  = (const float*)d_in[4];
  const float* Wv  = (const float*)d_in[5];
  const float* Wo  = (const float*)d_in[6];
  float* out = (float*)d_out;                 // [B,S,H] fp32

  char* ws = (char*)d_ws;
  size_t off = 0;
  auto alloc = [&](size_t elems) {
    u16* p = (u16*)(ws + off);
    off += ((elems * 2 + 255) & ~(size_t)255);
    return p;
  };
  u16* Xb  = alloc((size_t)4096 * 2304);
  u16* WqT = alloc((size_t)2048 * 2304);
  u16* WkT = alloc((size_t)1024 * 2304);
  u16* WvT = alloc((size_t)1024 * 2304);
  u16* WoT = alloc((size_t)2304 * 2048);
  u16* Qb  = alloc((size_t)4096 * 2048);
  u16* Kb  = alloc((size_t)4096 * 1024);
  u16* Vb  = alloc((size_t)4096 * 1024);
  u16* VTb = alloc((size_t)4096 * 1024);
  u16* AO  = alloc((size_t)4096 * 2048);
  if (off > ws_size) return;  // insufficient workspace -> leave zeros (loud failure)

  // hidden_states fp32 -> bf16
  {
    size_t n = (size_t)4096 * 2304;
    f32_to_bf16<<<(unsigned)((n / 4 + 255) / 256), 256, 0, stream>>>(X, Xb, n);
  }

  dim3 tb(32, 8);
  // weight transposes (fp32 -> bf16): W[K][N] -> WT[N][K]
  transpose_f32_bf16<<<dim3(2048 / 32, 2304 / 32), tb, 0, stream>>>(Wq, WqT, 2304, 2048);
  transpose_f32_bf16<<<dim3(1024 / 32, 2304 / 32), tb, 0, stream>>>(Wk, WkT, 2304, 1024);
  transpose_f32_bf16<<<dim3(1024 / 32, 2304 / 32), tb, 0, stream>>>(Wv, WvT, 2304, 1024);
  transpose_f32_bf16<<<dim3(2304 / 32, 2048 / 32), tb, 0, stream>>>(Wo, WoT, 2048, 2304);

  // projections (bf16 out)
  gemm_bt<false><<<dim3(2048 / 128, 4096 / 128), 256, 0, stream>>>(Xb, WqT, Qb, 4096, 2048, 2304);
  gemm_bt<false><<<dim3(1024 / 128, 4096 / 128), 256, 0, stream>>>(Xb, WkT, Kb, 4096, 1024, 2304);
  gemm_bt<false><<<dim3(1024 / 128, 4096 / 128), 256, 0, stream>>>(Xb, WvT, Vb, 4096, 1024, 2304);

  // RoPE (scale 1/16 folded into Q)
  rope_kernel<<<(4096 * 8 * 128) / 256, 256, 0, stream>>>(Qb, pos, 8, 2048, 1.0f / 16.0f);
  rope_kernel<<<(4096 * 4 * 128) / 256, 256, 0, stream>>>(Kb, pos, 4, 1024, 1.0f);

  // V -> VT[b][kv][d][s]
  transpose_bf16<<<dim3(1024 / 32, 2048 / 32, 2), tb, 0, stream>>>(Vb, VTb, 2048, 1024);

  // attention (bf16 out)
  attn_kernel<<<dim3(2048 / 64, 16), 256, 0, stream>>>(Qb, Kb, VTb, amask, AO);

  // output projection -> fp32 d_out
  gemm_bt<true><<<dim3(2304 / 128, 4096 / 128), 256, 0, stream>>>(AO, WoT, out, 4096, 2304, 2048);
}

// Round 3
// 433.162 us; speedup vs baseline: 1.6248x; 1.6248x over previous
//
#include <hip/hip_runtime.h>
#include <hip/hip_bf16.h>
#include <stdint.h>

typedef unsigned short u16;
typedef __attribute__((ext_vector_type(8))) short s16x8;
typedef __attribute__((ext_vector_type(4))) float f32x4;

#define B_ 2
#define S_ 2048
#define H_ 2304
#define NH_ 8
#define NKV_ 4
#define HD_ 256

__device__ __forceinline__ float bf2f(u16 u) {
  union { uint32_t i; float f; } x; x.i = ((uint32_t)u) << 16; return x.f;
}
__device__ __forceinline__ u16 f2bf(float f) {
  union { float f; uint32_t i; } x; x.f = f;
  uint32_t u = x.i;
  return (u16)((u + 0x7fffu + ((u >> 16) & 1u)) >> 16);
}

__device__ __forceinline__ void async16(const void* g, void* l) {
  __builtin_amdgcn_global_load_lds((const __attribute__((address_space(1))) uint32_t*)g,
                                   (__attribute__((address_space(3))) uint32_t*)l, 16, 0, 0);
}

__device__ __forceinline__ f32x4 mfma16(s16x8 a, s16x8 b, f32x4 c) {
  return __builtin_amdgcn_mfma_f32_16x16x32_bf16(a, b, c, 0, 0, 0);
}

// ---------------- fp32 -> bf16 elementwise convert ----------------
__global__ void f32_to_bf16(const float* __restrict__ in, u16* __restrict__ out, size_t n) {
  size_t i = ((size_t)blockIdx.x * blockDim.x + threadIdx.x) * 4;
  if (i + 3 < n) {
    float4 v = *(const float4*)(in + i);
    ushort4 o;
    o.x = f2bf(v.x); o.y = f2bf(v.y); o.z = f2bf(v.z); o.w = f2bf(v.w);
    *(ushort4*)(out + i) = o;
  }
}

// ---------------- transpose fp32 in -> bf16 out: in[R][C] -> out[C][R] ----------------
__global__ void transpose_f32_bf16(const float* __restrict__ in, u16* __restrict__ out, int R, int C) {
  __shared__ u16 tile[32][33];
  int c0 = blockIdx.x * 32, r0 = blockIdx.y * 32;
  int x = threadIdx.x, y = threadIdx.y;
#pragma unroll
  for (int j = 0; j < 32; j += 8)
    tile[y + j][x] = f2bf(in[(size_t)(r0 + y + j) * C + c0 + x]);
  __syncthreads();
#pragma unroll
  for (int j = 0; j < 32; j += 8)
    out[(size_t)(c0 + y + j) * R + r0 + x] = tile[x][y + j];
}

// ---------------- transpose bf16 -> bf16 (batched along z) ----------------
__global__ void transpose_bf16(const u16* __restrict__ in, u16* __restrict__ out, int R, int C) {
  __shared__ u16 tile[32][33];
  size_t bofs = (size_t)blockIdx.z * R * C;
  in += bofs; out += bofs;
  int c0 = blockIdx.x * 32, r0 = blockIdx.y * 32;
  int x = threadIdx.x, y = threadIdx.y;
#pragma unroll
  for (int j = 0; j < 32; j += 8)
    tile[y + j][x] = in[(size_t)(r0 + y + j) * C + c0 + x];
  __syncthreads();
#pragma unroll
  for (int j = 0; j < 32; j += 8)
    out[(size_t)(c0 + y + j) * R + r0 + x] = tile[x][y + j];
}

// ---------------- GEMM: C[M][N] = A[M][Kd] * BT[N][Kd]^T (bf16 in, bf16 or f32 out) ----
template <bool F32OUT>
__global__ __launch_bounds__(256) void gemm_bt(const u16* __restrict__ A, const u16* __restrict__ BT,
                                               void* __restrict__ Cout, int M, int N, int Kd) {
  __shared__ u16 As[128 * 32];
  __shared__ u16 Bs[128 * 32];
  int tid = threadIdx.x;
  int lane = tid & 63, wave = tid >> 6;
  int bm = blockIdx.y * 128, bn = blockIdx.x * 128;
  int wm = (wave >> 1) * 64, wn = (wave & 1) * 64;
  int fr = lane & 15, fq = lane >> 4;
  f32x4 zero4 = {0.f, 0.f, 0.f, 0.f};
  f32x4 acc[4][4];
#pragma unroll
  for (int i = 0; i < 4; i++)
#pragma unroll
    for (int j = 0; j < 4; j++) acc[i][j] = zero4;

  int arow = tid >> 2, aoff = (tid & 3) * 8;
  const u16* Ab = A + (size_t)(bm + arow) * Kd + aoff;
  const u16* Bb = BT + (size_t)(bn + arow) * Kd + aoff;
  char* AsB = (char*)As + wave * 1024;
  char* BsB = (char*)Bs + wave * 1024;

  for (int k0 = 0; k0 < Kd; k0 += 32) {
    async16(Ab + k0, AsB);
    async16(Ab + (size_t)64 * Kd + k0, AsB + 4096);
    async16(Bb + k0, BsB);
    async16(Bb + (size_t)64 * Kd + k0, BsB + 4096);
    __syncthreads();
    s16x8 af[4], bv[4];
#pragma unroll
    for (int i = 0; i < 4; i++) af[i] = *(const s16x8*)&As[(wm + i * 16 + fr) * 32 + fq * 8];
#pragma unroll
    for (int j = 0; j < 4; j++) bv[j] = *(const s16x8*)&Bs[(wn + j * 16 + fr) * 32 + fq * 8];
#pragma unroll
    for (int i = 0; i < 4; i++)
#pragma unroll
      for (int j = 0; j < 4; j++)
        acc[i][j] = mfma16(af[i], bv[j], acc[i][j]);
    __syncthreads();
  }
#pragma unroll
  for (int i = 0; i < 4; i++)
#pragma unroll
    for (int j = 0; j < 4; j++)
#pragma unroll
      for (int r = 0; r < 4; r++) {
        int row = bm + wm + i * 16 + fq * 4 + r;
        int col = bn + wn + j * 16 + fr;
        if (F32OUT) ((float*)Cout)[(size_t)row * N + col] = acc[i][j][r];
        else        ((u16*)Cout)[(size_t)row * N + col] = f2bf(acc[i][j][r]);
      }
}

// ---------------- RoPE in-place (+optional scale), one thread per (row,head,pair) ----
__global__ void rope_kernel(u16* __restrict__ buf, const int* __restrict__ pos_ids,
                            int nheads, int rowlen, float scale) {
  int idx = blockIdx.x * blockDim.x + threadIdx.x;
  int d = idx & 127;
  int hn = idx >> 7;
  int h = hn % nheads;
  int row = hn / nheads;
  float pos = (float)pos_ids[row];
  double invf = exp((double)d * -0.07195578415606394); // -ln(10000)/128
  double f = (double)pos * invf;
  double sd, cd;
  sincos(f, &sd, &cd);
  float sv = (float)sd, cv = (float)cd;
  size_t base = (size_t)row * rowlen + (size_t)h * HD_ + d;
  float a = bf2f(buf[base]);
  float b = bf2f(buf[base + 128]);
  buf[base]       = f2bf((a * cv - b * sv) * scale);
  buf[base + 128] = f2bf((b * cv + a * sv) * scale);
}

// ---------------- flash attention, softcap, fixed-max softmax, swizzled LDS ----------
// grid: (32, 16). block 256 = 4 waves x 16 q-rows. KVBLK=32, double-buffered.
__global__ __launch_bounds__(256) void attn_kernel(const u16* __restrict__ Q, const u16* __restrict__ K,
                                                   const u16* __restrict__ VT, const int* __restrict__ amask,
                                                   u16* __restrict__ O) {
  __shared__ u16 Kl[2][32 * 256];   // [buf][key][hd]  16 KiB each, swizzled ^((key&7)<<3)
  __shared__ u16 Vl[2][256 * 32];   // [buf][hd][key]  16 KiB each, swizzled ^((hd&3)<<3)
  __shared__ u16 Pl[4][16 * 32];    // per-wave P, swizzled ^((qrow&3)<<3)
  // complementary-qt pairing: co-resident blocks (y, y+8) get qt = x and 31-x
  int qt = (blockIdx.y & 8) ? (31 - (int)blockIdx.x) : (int)blockIdx.x;
  int bh = blockIdx.y;
  int b = bh >> 3, h = bh & 7, g = h >> 1;
  int tid = threadIdx.x, lane = tid & 63, wave = tid >> 6;
  int fr = lane & 15, fq = lane >> 4;
  int q0 = qt * 64;

  // Q fragments in registers (Q already scaled by 1/16 in rope)
  s16x8 qf[8];
  const u16* qb = Q + (size_t)(b * S_ + q0 + wave * 16 + fr) * 2048 + h * 256 + fq * 8;
#pragma unroll
  for (int kk = 0; kk < 8; kk++) qf[kk] = *(const s16x8*)(qb + kk * 32);

  f32x4 zero4 = {0.f, 0.f, 0.f, 0.f};
  f32x4 oacc[16];
#pragma unroll
  for (int i = 0; i < 16; i++) oacc[i] = zero4;
  float l_run[4] = {0.f, 0.f, 0.f, 0.f};

  const u16* Kbase = K + (size_t)b * S_ * 1024 + g * 256;
  const u16* Vbase = VT + (size_t)(b * 4 + g) * 256 * S_;

  // staging: per wave, K rows wave*8..+7 (512B each), V rows wave*64..+63 (64B each)
  auto stage = [&](int buf, int k0) {
#pragma unroll
    for (int it = 0; it < 4; ++it) {
      int rl = it * 2 + (lane >> 5);                         // K row within tile's wave slice
      int kce = ((lane & 31) * 8) ^ ((rl & 7) << 3);         // pre-swizzled source col
      async16(Kbase + (size_t)(k0 + wave * 8 + rl) * 1024 + kce,
              (char*)&Kl[buf][0] + wave * 4096 + it * 1024);
      int dl = wave * 64 + it * 16 + (lane >> 2);            // V row (hd)
      int vce = ((lane & 3) * 8) ^ (((lane >> 2) & 3) << 3);
      async16(Vbase + (size_t)dl * 2048 + k0 + vce,
              (char*)&Vl[buf][0] + wave * 4096 + it * 1024);
    }
  };

  int nt = 2 * qt + 2;                                        // 32-key tiles
  stage(0, 0);
  __syncthreads();                                            // drains vmcnt
  int buf = 0;
  int ksw = (fr & 7) << 3;                                    // K read swizzle (same for both n)
  int vsw = (fr & 3) << 3;                                    // V read swizzle
  for (int t = 0; t < nt; ++t) {
    int k0 = t * 32;
    if (t + 1 < nt) stage(buf ^ 1, k0 + 32);                  // issue-ahead into other buffer
    int am0 = amask[b * S_ + k0 + fr];
    int am1 = amask[b * S_ + k0 + 16 + fr];

    f32x4 s0 = zero4, s1 = zero4;
#pragma unroll
    for (int kk = 0; kk < 8; kk++) {
      s16x8 b0 = *(const s16x8*)&Kl[buf][fr * 256 + ((kk * 32 + fq * 8) ^ ksw)];
      s16x8 b1 = *(const s16x8*)&Kl[buf][(16 + fr) * 256 + ((kk * 32 + fq * 8) ^ ksw)];
      s0 = mfma16(qf[kk], b0, s0);
      s1 = mfma16(qf[kk], b1, s1);
    }

    bool needmask = (t >= nt - 2);
#pragma unroll
    for (int r = 0; r < 4; r++) {
      int qrow = fq * 4 + r;
      int qg = q0 + wave * 16 + qrow;
      // p = exp(50*tanh(s/50) - 50) = exp(-100/(exp(0.04*s)+1))   [fixed max = 50]
      float e20 = __expf(s0[r] * 0.04f);
      float e21 = __expf(s1[r] * 0.04f);
      float p0 = __expf(-100.f / (e20 + 1.f));
      float p1 = __expf(-100.f / (e21 + 1.f));
      bool ok0 = (am0 > 0) && (!needmask || (k0 + fr) <= qg);
      bool ok1 = (am1 > 0) && (!needmask || (k0 + 16 + fr) <= qg);
      p0 = ok0 ? p0 : 0.f;
      p1 = ok1 ? p1 : 0.f;
      float lsum = p0 + p1;
      Pl[wave][qrow * 32 + (fr ^ (r << 3))] = f2bf(p0);
      Pl[wave][qrow * 32 + ((16 + fr) ^ (r << 3))] = f2bf(p1);
#pragma unroll
      for (int off = 1; off < 16; off <<= 1) lsum += __shfl_xor(lsum, off);
      l_run[r] += lsum;
    }
    asm volatile("s_waitcnt lgkmcnt(0)" ::: "memory");
    __builtin_amdgcn_sched_barrier(0);

    s16x8 pf = *(const s16x8*)&Pl[wave][fr * 32 + ((fq * 8) ^ vsw)];
#pragma unroll
    for (int df = 0; df < 16; df++) {
      s16x8 vv = *(const s16x8*)&Vl[buf][(df * 16 + fr) * 32 + ((fq * 8) ^ vsw)];
      oacc[df] = mfma16(pf, vv, oacc[df]);
    }
    __syncthreads();                                          // drains next-tile loads too
    buf ^= 1;
  }

  float rinv[4];
#pragma unroll
  for (int r = 0; r < 4; r++) rinv[r] = 1.0f / l_run[r];
#pragma unroll
  for (int df = 0; df < 16; df++) {
#pragma unroll
    for (int r = 0; r < 4; r++) {
      float ov = oacc[df][r] * rinv[r];
      O[(size_t)(b * S_ + q0 + wave * 16 + fq * 4 + r) * 2048 + h * 256 + df * 16 + fr] = f2bf(ov);
    }
  }
}

extern "C" void kernel_launch(void* const* d_in, const int* in_sizes, int n_in,
                              void* d_out, int out_size, void* d_ws, size_t ws_size,
                              hipStream_t stream) {
  const float* X   = (const float*)d_in[0];   // [B,S,H] fp32
  const int* amask = (const int*)d_in[1];
  const int* pos   = (const int*)d_in[2];
  const float* Wq  = (const float*)d_in[3];   // [H, NH*HD] fp32
  const float* Wk  = (const float*)d_in[4];
  const float* Wv  = (const float*)d_in[5];
  const float* Wo  = (const float*)d_in[6];
  float* out = (float*)d_out;                 // [B,S,H] fp32

  char* ws = (char*)d_ws;
  size_t off = 0;
  auto alloc = [&](size_t elems) {
    u16* p = (u16*)(ws + off);
    off += ((elems * 2 + 255) & ~(size_t)255);
    return p;
  };
  u16* Xb  = alloc((size_t)4096 * 2304);
  u16* WqT = alloc((size_t)2048 * 2304);
  u16* WkT = alloc((size_t)1024 * 2304);
  u16* WvT = alloc((size_t)1024 * 2304);
  u16* WoT = alloc((size_t)2304 * 2048);
  u16* Qb  = alloc((size_t)4096 * 2048);
  u16* Kb  = alloc((size_t)4096 * 1024);
  u16* Vb  = alloc((size_t)4096 * 1024);
  u16* VTb = alloc((size_t)4096 * 1024);
  u16* AO  = alloc((size_t)4096 * 2048);
  if (off > ws_size) return;  // insufficient workspace -> leave zeros (loud failure)

  // hidden_states fp32 -> bf16
  {
    size_t n = (size_t)4096 * 2304;
    f32_to_bf16<<<(unsigned)((n / 4 + 255) / 256), 256, 0, stream>>>(X, Xb, n);
  }

  dim3 tb(32, 8);
  // weight transposes (fp32 -> bf16): W[K][N] -> WT[N][K]
  transpose_f32_bf16<<<dim3(2048 / 32, 2304 / 32), tb, 0, stream>>>(Wq, WqT, 2304, 2048);
  transpose_f32_bf16<<<dim3(1024 / 32, 2304 / 32), tb, 0, stream>>>(Wk, WkT, 2304, 1024);
  transpose_f32_bf16<<<dim3(1024 / 32, 2304 / 32), tb, 0, stream>>>(Wv, WvT, 2304, 1024);
  transpose_f32_bf16<<<dim3(2304 / 32, 2048 / 32), tb, 0, stream>>>(Wo, WoT, 2048, 2304);

  // projections (bf16 out)
  gemm_bt<false><<<dim3(2048 / 128, 4096 / 128), 256, 0, stream>>>(Xb, WqT, Qb, 4096, 2048, 2304);
  gemm_bt<false><<<dim3(1024 / 128, 4096 / 128), 256, 0, stream>>>(Xb, WkT, Kb, 4096, 1024, 2304);
  gemm_bt<false><<<dim3(1024 / 128, 4096 / 128), 256, 0, stream>>>(Xb, WvT, Vb, 4096, 1024, 2304);

  // RoPE (scale 1/16 folded into Q)
  rope_kernel<<<(4096 * 8 * 128) / 256, 256, 0, stream>>>(Qb, pos, 8, 2048, 1.0f / 16.0f);
  rope_kernel<<<(4096 * 4 * 128) / 256, 256, 0, stream>>>(Kb, pos, 4, 1024, 1.0f);

  // V -> VT[b][kv][d][s]
  transpose_bf16<<<dim3(1024 / 32, 2048 / 32, 2), tb, 0, stream>>>(Vb, VTb, 2048, 1024);

  // attention (bf16 out)
  attn_kernel<<<dim3(32, 16), 256, 0, stream>>>(Qb, Kb, VTb, amask, AO);

  // output projection -> fp32 d_out
  gemm_bt<true><<<dim3(2304 / 128, 4096 / 128), 256, 0, stream>>>(AO, WoT, out, 4096, 2304, 2048);
}

// Round 4
// 368.211 us; speedup vs baseline: 1.9115x; 1.1764x over previous
//
#include <hip/hip_runtime.h>
#include <hip/hip_bf16.h>
#include <stdint.h>

typedef unsigned short u16;
typedef __attribute__((ext_vector_type(8))) short s16x8;
typedef __attribute__((ext_vector_type(4))) float f32x4;

#define B_ 2
#define S_ 2048
#define H_ 2304
#define NH_ 8
#define NKV_ 4
#define HD_ 256

__device__ __forceinline__ float bf2f(u16 u) {
  union { uint32_t i; float f; } x; x.i = ((uint32_t)u) << 16; return x.f;
}
__device__ __forceinline__ u16 f2bf(float f) {
  union { float f; uint32_t i; } x; x.f = f;
  uint32_t u = x.i;
  return (u16)((u + 0x7fffu + ((u >> 16) & 1u)) >> 16);
}

__device__ __forceinline__ void async16(const void* g, void* l) {
  __builtin_amdgcn_global_load_lds((const __attribute__((address_space(1))) uint32_t*)g,
                                   (__attribute__((address_space(3))) uint32_t*)l, 16, 0, 0);
}

__device__ __forceinline__ f32x4 mfma16(s16x8 a, s16x8 b, f32x4 c) {
  return __builtin_amdgcn_mfma_f32_16x16x32_bf16(a, b, c, 0, 0, 0);
}

// ---------------- fp32 -> bf16 elementwise convert ----------------
__global__ void f32_to_bf16(const float* __restrict__ in, u16* __restrict__ out, size_t n) {
  size_t i = ((size_t)blockIdx.x * blockDim.x + threadIdx.x) * 4;
  if (i + 3 < n) {
    float4 v = *(const float4*)(in + i);
    ushort4 o;
    o.x = f2bf(v.x); o.y = f2bf(v.y); o.z = f2bf(v.z); o.w = f2bf(v.w);
    *(ushort4*)(out + i) = o;
  }
}

// ---------------- transpose fp32 in -> bf16 out: in[R][C] -> out[C][R] ----------------
__global__ void transpose_f32_bf16(const float* __restrict__ in, u16* __restrict__ out, int R, int C) {
  __shared__ u16 tile[32][33];
  int c0 = blockIdx.x * 32, r0 = blockIdx.y * 32;
  int x = threadIdx.x, y = threadIdx.y;
#pragma unroll
  for (int j = 0; j < 32; j += 8)
    tile[y + j][x] = f2bf(in[(size_t)(r0 + y + j) * C + c0 + x]);
  __syncthreads();
#pragma unroll
  for (int j = 0; j < 32; j += 8)
    out[(size_t)(c0 + y + j) * R + r0 + x] = tile[x][y + j];
}

// ------- strided-batch bf16 transpose: in[z*zin + r*istride + c] -> out[z*zout + c*R + r] -------
__global__ void transpose_bf16_s(const u16* __restrict__ in, u16* __restrict__ out, int R, int C,
                                 int istride, size_t zin, size_t zout) {
  __shared__ u16 tile[32][33];
  in += (size_t)blockIdx.z * zin;
  out += (size_t)blockIdx.z * zout;
  int c0 = blockIdx.x * 32, r0 = blockIdx.y * 32;
  int x = threadIdx.x, y = threadIdx.y;
#pragma unroll
  for (int j = 0; j < 32; j += 8)
    tile[y + j][x] = in[(size_t)(r0 + y + j) * istride + c0 + x];
  __syncthreads();
#pragma unroll
  for (int j = 0; j < 32; j += 8)
    out[(size_t)(c0 + y + j) * R + r0 + x] = tile[x][y + j];
}

// ---------------- GEMM: C[M][N] = A[M][Kd] * BT[N][Kd]^T (bf16 in, bf16 or f32 out) ----
// XCD-aware tile swizzle: requires (gridDim.x*gridDim.y) % 8 == 0.
template <bool F32OUT>
__global__ __launch_bounds__(256) void gemm_bt(const u16* __restrict__ A, const u16* __restrict__ BT,
                                               void* __restrict__ Cout, int M, int N, int Kd) {
  __shared__ u16 As[128 * 32];
  __shared__ u16 Bs[128 * 32];
  int tid = threadIdx.x;
  int lane = tid & 63, wave = tid >> 6;
  int nTiles = gridDim.x * gridDim.y;
  int bid = blockIdx.y * gridDim.x + blockIdx.x;
  int tile = (bid & 7) * (nTiles >> 3) + (bid >> 3);
  int bn = (tile % gridDim.x) * 128;
  int bm = (tile / gridDim.x) * 128;
  int wm = (wave >> 1) * 64, wn = (wave & 1) * 64;
  int fr = lane & 15, fq = lane >> 4;
  f32x4 zero4 = {0.f, 0.f, 0.f, 0.f};
  f32x4 acc[4][4];
#pragma unroll
  for (int i = 0; i < 4; i++)
#pragma unroll
    for (int j = 0; j < 4; j++) acc[i][j] = zero4;

  int arow = tid >> 2, aoff = (tid & 3) * 8;
  const u16* Ab = A + (size_t)(bm + arow) * Kd + aoff;
  const u16* Bb = BT + (size_t)(bn + arow) * Kd + aoff;
  char* AsB = (char*)As + wave * 1024;
  char* BsB = (char*)Bs + wave * 1024;

  for (int k0 = 0; k0 < Kd; k0 += 32) {
    async16(Ab + k0, AsB);
    async16(Ab + (size_t)64 * Kd + k0, AsB + 4096);
    async16(Bb + k0, BsB);
    async16(Bb + (size_t)64 * Kd + k0, BsB + 4096);
    __syncthreads();
    s16x8 af[4], bv[4];
#pragma unroll
    for (int i = 0; i < 4; i++) af[i] = *(const s16x8*)&As[(wm + i * 16 + fr) * 32 + fq * 8];
#pragma unroll
    for (int j = 0; j < 4; j++) bv[j] = *(const s16x8*)&Bs[(wn + j * 16 + fr) * 32 + fq * 8];
#pragma unroll
    for (int i = 0; i < 4; i++)
#pragma unroll
      for (int j = 0; j < 4; j++)
        acc[i][j] = mfma16(af[i], bv[j], acc[i][j]);
    __syncthreads();
  }
#pragma unroll
  for (int i = 0; i < 4; i++)
#pragma unroll
    for (int j = 0; j < 4; j++)
#pragma unroll
      for (int r = 0; r < 4; r++) {
        int row = bm + wm + i * 16 + fq * 4 + r;
        int col = bn + wn + j * 16 + fr;
        if (F32OUT) ((float*)Cout)[(size_t)row * N + col] = acc[i][j][r];
        else        ((u16*)Cout)[(size_t)row * N + col] = f2bf(acc[i][j][r]);
      }
}

// ---------------- RoPE in-place on strided buffer (+optional scale) ----------------
__global__ void rope_kernel(u16* __restrict__ buf, const int* __restrict__ pos_ids,
                            int nheads, int rowstride, int colofs, float scale) {
  int idx = blockIdx.x * blockDim.x + threadIdx.x;
  int d = idx & 127;
  int hn = idx >> 7;
  int h = hn % nheads;
  int row = hn / nheads;
  float pos = (float)pos_ids[row];
  double invf = exp((double)d * -0.07195578415606394); // -ln(10000)/128
  double f = (double)pos * invf;
  double sd, cd;
  sincos(f, &sd, &cd);
  float sv = (float)sd, cv = (float)cd;
  size_t base = (size_t)row * rowstride + colofs + (size_t)h * HD_ + d;
  float a = bf2f(buf[base]);
  float b = bf2f(buf[base + 128]);
  buf[base]       = f2bf((a * cv - b * sv) * scale);
  buf[base + 128] = f2bf((b * cv + a * sv) * scale);
}

// ---------------- flash attention, softcap, fixed-max softmax, swizzled LDS ----------
// QKV fused layout: row stride 4096; Q at col 0, K at col 2048 (V consumed via VT).
// grid: (32, 16). block 256 = 4 waves x 16 q-rows. KVBLK=32, double-buffered.
__global__ __launch_bounds__(256) void attn_kernel(const u16* __restrict__ QKV, const u16* __restrict__ VT,
                                                   const int* __restrict__ amask, u16* __restrict__ O) {
  __shared__ u16 Kl[2][32 * 256];   // [buf][key][hd]  16 KiB each, swizzled ^((key&7)<<3)
  __shared__ u16 Vl[2][256 * 32];   // [buf][hd][key]  16 KiB each, swizzled ^((hd&3)<<3)
  __shared__ u16 Pl[4][16 * 40];    // per-wave P, rows padded to 40 u16 (80B) -> conflict-free
  // complementary-qt pairing: co-resident blocks (y, y+8) get qt = x and 31-x
  int qt = (blockIdx.y & 8) ? (31 - (int)blockIdx.x) : (int)blockIdx.x;
  int bh = blockIdx.y;
  int b = bh >> 3, h = bh & 7, g = h >> 1;
  int tid = threadIdx.x, lane = tid & 63, wave = tid >> 6;
  int fr = lane & 15, fq = lane >> 4;
  int q0 = qt * 64;

  // Q fragments in registers (Q already scaled by 1/16 in rope)
  s16x8 qf[8];
  const u16* qb = QKV + (size_t)(b * S_ + q0 + wave * 16 + fr) * 4096 + h * 256 + fq * 8;
#pragma unroll
  for (int kk = 0; kk < 8; kk++) qf[kk] = *(const s16x8*)(qb + kk * 32);

  f32x4 zero4 = {0.f, 0.f, 0.f, 0.f};
  f32x4 oacc[16];
#pragma unroll
  for (int i = 0; i < 16; i++) oacc[i] = zero4;
  f32x4 lacc = zero4;                                     // softmax denominator via ones-MFMA
  s16x8 onesv;
#pragma unroll
  for (int i = 0; i < 8; i++) onesv[i] = (short)0x3F80;   // bf16 1.0

  const u16* Kbase = QKV + (size_t)b * S_ * 4096 + 2048 + g * 256;
  const u16* Vbase = VT + (size_t)(b * 4 + g) * 256 * S_;

  // staging: per wave, K rows wave*8..+7 (512B each), V rows wave*64..+63 (64B each)
  auto stage = [&](int buf, int k0) {
#pragma unroll
    for (int it = 0; it < 4; ++it) {
      int rl = it * 2 + (lane >> 5);                         // K row within tile's wave slice
      int kce = ((lane & 31) * 8) ^ ((rl & 7) << 3);         // pre-swizzled source col
      async16(Kbase + (size_t)(k0 + wave * 8 + rl) * 4096 + kce,
              (char*)&Kl[buf][0] + wave * 4096 + it * 1024);
      int dl = wave * 64 + it * 16 + (lane >> 2);            // V row (hd)
      int vce = ((lane & 3) * 8) ^ (((lane >> 2) & 3) << 3);
      async16(Vbase + (size_t)dl * 2048 + k0 + vce,
              (char*)&Vl[buf][0] + wave * 4096 + it * 1024);
    }
  };

  int nt = 2 * qt + 2;                                        // 32-key tiles
  stage(0, 0);
  __syncthreads();                                            // drains vmcnt
  int buf = 0;
  int ksw = (fr & 7) << 3;                                    // K read swizzle
  int vsw = (fr & 3) << 3;                                    // V read swizzle
  for (int t = 0; t < nt; ++t) {
    int k0 = t * 32;
    if (t + 1 < nt) stage(buf ^ 1, k0 + 32);                  // issue-ahead into other buffer
    int am0 = amask[b * S_ + k0 + fr];
    int am1 = amask[b * S_ + k0 + 16 + fr];

    f32x4 s0 = zero4, s1 = zero4;
#pragma unroll
    for (int kk = 0; kk < 8; kk++) {
      s16x8 b0 = *(const s16x8*)&Kl[buf][fr * 256 + ((kk * 32 + fq * 8) ^ ksw)];
      s16x8 b1 = *(const s16x8*)&Kl[buf][(16 + fr) * 256 + ((kk * 32 + fq * 8) ^ ksw)];
      s0 = mfma16(qf[kk], b0, s0);
      s1 = mfma16(qf[kk], b1, s1);
    }

    bool needmask = (t >= nt - 2);
#pragma unroll
    for (int r = 0; r < 4; r++) {
      int qrow = fq * 4 + r;
      int qg = q0 + wave * 16 + qrow;
      // p = exp(50*tanh(s/50) - 50) = exp(-100/(exp(0.04*s)+1))   [fixed max = 50]
      float e20 = __expf(s0[r] * 0.04f);
      float e21 = __expf(s1[r] * 0.04f);
      float p0 = __expf(-100.f / (e20 + 1.f));
      float p1 = __expf(-100.f / (e21 + 1.f));
      bool ok0 = (am0 > 0) && (!needmask || (k0 + fr) <= qg);
      bool ok1 = (am1 > 0) && (!needmask || (k0 + 16 + fr) <= qg);
      p0 = ok0 ? p0 : 0.f;
      p1 = ok1 ? p1 : 0.f;
      Pl[wave][qrow * 40 + fr] = f2bf(p0);
      Pl[wave][qrow * 40 + 16 + fr] = f2bf(p1);
    }
    asm volatile("s_waitcnt lgkmcnt(0)" ::: "memory");
    __builtin_amdgcn_sched_barrier(0);

    s16x8 pf = *(const s16x8*)&Pl[wave][fr * 40 + fq * 8];
    lacc = mfma16(pf, onesv, lacc);                           // row-sum of P (all cols equal)
#pragma unroll
    for (int df = 0; df < 16; df++) {
      s16x8 vv = *(const s16x8*)&Vl[buf][(df * 16 + fr) * 32 + ((fq * 8) ^ vsw)];
      oacc[df] = mfma16(pf, vv, oacc[df]);
    }
    __syncthreads();                                          // drains next-tile loads too
    buf ^= 1;
  }

  float rinv[4];
#pragma unroll
  for (int r = 0; r < 4; r++) rinv[r] = 1.0f / lacc[r];
#pragma unroll
  for (int df = 0; df < 16; df++) {
#pragma unroll
    for (int r = 0; r < 4; r++) {
      float ov = oacc[df][r] * rinv[r];
      O[(size_t)(b * S_ + q0 + wave * 16 + fq * 4 + r) * 2048 + h * 256 + df * 16 + fr] = f2bf(ov);
    }
  }
}

extern "C" void kernel_launch(void* const* d_in, const int* in_sizes, int n_in,
                              void* d_out, int out_size, void* d_ws, size_t ws_size,
                              hipStream_t stream) {
  const float* X   = (const float*)d_in[0];   // [B,S,H] fp32
  const int* amask = (const int*)d_in[1];
  const int* pos   = (const int*)d_in[2];
  const float* Wq  = (const float*)d_in[3];   // [H, NH*HD] fp32
  const float* Wk  = (const float*)d_in[4];
  const float* Wv  = (const float*)d_in[5];
  const float* Wo  = (const float*)d_in[6];
  float* out = (float*)d_out;                 // [B,S,H] fp32

  char* ws = (char*)d_ws;
  size_t off = 0;
  auto alloc = [&](size_t elems) {
    u16* p = (u16*)(ws + off);
    off += ((elems * 2 + 255) & ~(size_t)255);
    return p;
  };
  u16* Xb   = alloc((size_t)4096 * 2304);
  u16* WqT  = alloc((size_t)2048 * 2304);   // WqT/WkT/WvT contiguous => fused [4096][2304] B^T
  u16* WkT  = alloc((size_t)1024 * 2304);
  u16* WvT  = alloc((size_t)1024 * 2304);
  u16* WoT  = alloc((size_t)2304 * 2048);
  u16* QKV  = alloc((size_t)4096 * 4096);   // fused projection output [4096][Q|K|V]
  u16* VTb  = alloc((size_t)4096 * 1024);
  u16* AO   = alloc((size_t)4096 * 2048);
  if (off > ws_size) return;  // insufficient workspace -> leave zeros (loud failure)

  // hidden_states fp32 -> bf16
  {
    size_t n = (size_t)4096 * 2304;
    f32_to_bf16<<<(unsigned)((n / 4 + 255) / 256), 256, 0, stream>>>(X, Xb, n);
  }

  dim3 tb(32, 8);
  // weight transposes (fp32 -> bf16): W[K][N] -> WT[N][K]
  transpose_f32_bf16<<<dim3(2048 / 32, 2304 / 32), tb, 0, stream>>>(Wq, WqT, 2304, 2048);
  transpose_f32_bf16<<<dim3(1024 / 32, 2304 / 32), tb, 0, stream>>>(Wk, WkT, 2304, 1024);
  transpose_f32_bf16<<<dim3(1024 / 32, 2304 / 32), tb, 0, stream>>>(Wv, WvT, 2304, 1024);
  transpose_f32_bf16<<<dim3(2304 / 32, 2048 / 32), tb, 0, stream>>>(Wo, WoT, 2048, 2304);

  // fused QKV projection: [4096][2304] x [4096][2304]^T -> [4096][4096] bf16
  gemm_bt<false><<<dim3(4096 / 128, 4096 / 128), 256, 0, stream>>>(Xb, WqT, QKV, 4096, 4096, 2304);

  // RoPE in-place on fused buffer (scale 1/16 folded into Q)
  rope_kernel<<<(4096 * 8 * 128) / 256, 256, 0, stream>>>(QKV, pos, 8, 4096, 0, 1.0f / 16.0f);
  rope_kernel<<<(4096 * 4 * 128) / 256, 256, 0, stream>>>(QKV, pos, 4, 4096, 2048, 1.0f);

  // V (QKV cols 3072..4095) -> VT[b][kv][d][s]
  transpose_bf16_s<<<dim3(1024 / 32, 2048 / 32, 2), tb, 0, stream>>>(
      QKV + 3072, VTb, 2048, 1024, 4096, (size_t)2048 * 4096, (size_t)1024 * 2048);

  // attention (bf16 out)
  attn_kernel<<<dim3(32, 16), 256, 0, stream>>>(QKV, VTb, amask, AO);

  // output projection -> fp32 d_out
  gemm_bt<true><<<dim3(2304 / 128, 4096 / 128), 256, 0, stream>>>(AO, WoT, out, 4096, 2304, 2048);
}

// Round 5
// 310.346 us; speedup vs baseline: 2.2679x; 1.1865x over previous
//
#include <hip/hip_runtime.h>
#include <hip/hip_bf16.h>
#include <stdint.h>

typedef unsigned short u16;
typedef __attribute__((ext_vector_type(8))) short s16x8;
typedef __attribute__((ext_vector_type(4))) float f32x4;

#define B_ 2
#define S_ 2048
#define H_ 2304
#define NH_ 8
#define NKV_ 4
#define HD_ 256

__device__ __forceinline__ float bf2f(u16 u) {
  union { uint32_t i; float f; } x; x.i = ((uint32_t)u) << 16; return x.f;
}
__device__ __forceinline__ u16 f2bf(float f) {
  union { float f; uint32_t i; } x; x.f = f;
  uint32_t u = x.i;
  return (u16)((u + 0x7fffu + ((u >> 16) & 1u)) >> 16);
}

__device__ __forceinline__ void async16(const void* g, void* l) {
  __builtin_amdgcn_global_load_lds((const __attribute__((address_space(1))) uint32_t*)g,
                                   (__attribute__((address_space(3))) uint32_t*)l, 16, 0, 0);
}

__device__ __forceinline__ f32x4 mfma16(s16x8 a, s16x8 b, f32x4 c) {
  return __builtin_amdgcn_mfma_f32_16x16x32_bf16(a, b, c, 0, 0, 0);
}

// ---------------- fp32 -> bf16 elementwise convert ----------------
__global__ void f32_to_bf16(const float* __restrict__ in, u16* __restrict__ out, size_t n) {
  size_t i = ((size_t)blockIdx.x * blockDim.x + threadIdx.x) * 4;
  if (i + 3 < n) {
    float4 v = *(const float4*)(in + i);
    ushort4 o;
    o.x = f2bf(v.x); o.y = f2bf(v.y); o.z = f2bf(v.z); o.w = f2bf(v.w);
    *(ushort4*)(out + i) = o;
  }
}

// ---------------- transpose fp32 in -> bf16 out: in[R][C] -> out[C][R] ----------------
__global__ void transpose_f32_bf16(const float* __restrict__ in, u16* __restrict__ out, int R, int C) {
  __shared__ u16 tile[32][33];
  int c0 = blockIdx.x * 32, r0 = blockIdx.y * 32;
  int x = threadIdx.x, y = threadIdx.y;
#pragma unroll
  for (int j = 0; j < 32; j += 8)
    tile[y + j][x] = f2bf(in[(size_t)(r0 + y + j) * C + c0 + x]);
  __syncthreads();
#pragma unroll
  for (int j = 0; j < 32; j += 8)
    out[(size_t)(c0 + y + j) * R + r0 + x] = tile[x][y + j];
}

// ------- strided-batch bf16 transpose: in[z*zin + r*istride + c] -> out[z*zout + c*R + r] -------
__global__ void transpose_bf16_s(const u16* __restrict__ in, u16* __restrict__ out, int R, int C,
                                 int istride, size_t zin, size_t zout) {
  __shared__ u16 tile[32][33];
  in += (size_t)blockIdx.z * zin;
  out += (size_t)blockIdx.z * zout;
  int c0 = blockIdx.x * 32, r0 = blockIdx.y * 32;
  int x = threadIdx.x, y = threadIdx.y;
#pragma unroll
  for (int j = 0; j < 32; j += 8)
    tile[y + j][x] = in[(size_t)(r0 + y + j) * istride + c0 + x];
  __syncthreads();
#pragma unroll
  for (int j = 0; j < 32; j += 8)
    out[(size_t)(c0 + y + j) * R + r0 + x] = tile[x][y + j];
}

// ================= 256x256 deep-pipelined GEMM: C = A[M][Kd] * BT[N][Kd]^T =================
// 512 threads = 8 waves (2M x 4N), BK=64, LDS 128 KiB double-buffered.
// Counted vmcnt(8): next K-tile's 8 global_load_lds stay in flight across the barrier.
// LDS XOR-swizzle (16B granule ^ (row&7)): pre-swizzled global source + swizzled ds_read.
template <bool F32OUT>
__global__ __launch_bounds__(512) void gemm256(const u16* __restrict__ A, const u16* __restrict__ BT,
                                               void* __restrict__ Cout, int M, int N, int Kd) {
  __shared__ u16 As[2][256 * 64];
  __shared__ u16 Bs[2][256 * 64];
  int tid = threadIdx.x, lane = tid & 63, wave = tid >> 6;
  int nT = gridDim.x * gridDim.y;
  int bid = blockIdx.y * gridDim.x + blockIdx.x;
  int tile = (bid & 7) * (nT >> 3) + (bid >> 3);        // XCD swizzle (nT % 8 == 0)
  int bn = (tile % gridDim.x) * 256;
  int bm = (tile / gridDim.x) * 256;
  int wm = (wave >> 2) * 128, wn = (wave & 3) * 64;
  int fr = lane & 15, fq = lane >> 4;
  f32x4 acc[8][4];
#pragma unroll
  for (int i = 0; i < 8; i++)
#pragma unroll
    for (int j = 0; j < 4; j++) acc[i][j] = (f32x4){0.f, 0.f, 0.f, 0.f};

  // staging geometry: thread t, inst i loads row i*64 + (t>>3), 16B-granule (t&7)^(row&7)
  int srow = tid >> 3, sslot = tid & 7;
  int scol = (sslot * 8) ^ ((srow & 7) << 3);           // pre-swizzled source col (u16 units)
  const u16* Ab = A + (size_t)(bm + srow) * Kd + scol;
  const u16* Bb = BT + (size_t)(bn + srow) * Kd + scol;

  auto stage = [&](int buf, int k0) {
#pragma unroll
    for (int i = 0; i < 4; i++) {
      async16(Ab + (size_t)i * 64 * Kd + k0, (char*)&As[buf][0] + wave * 1024 + i * 8192);
      async16(Bb + (size_t)i * 64 * Kd + k0, (char*)&Bs[buf][0] + wave * 1024 + i * 8192);
    }
  };

  int NT = Kd >> 6;
  int rsw = (fr & 7) << 3;                              // read swizzle (u16 units)
  stage(0, 0);
  for (int t = 0; t < NT; ++t) {
    if (t + 1 < NT) {
      stage((t + 1) & 1, (t + 1) << 6);
      asm volatile("s_waitcnt vmcnt(8)" ::: "memory");  // K-tile t landed; t+1 in flight
    } else {
      asm volatile("s_waitcnt vmcnt(0)" ::: "memory");
    }
    __builtin_amdgcn_sched_barrier(0);
    __builtin_amdgcn_s_barrier();
    __builtin_amdgcn_sched_barrier(0);
    const u16* Ap = &As[t & 1][0];
    const u16* Bp = &Bs[t & 1][0];
    __builtin_amdgcn_s_setprio(1);
    s16x8 bfr[4][2];
#pragma unroll
    for (int j = 0; j < 4; j++)
#pragma unroll
      for (int s = 0; s < 2; s++)
        bfr[j][s] = *(const s16x8*)&Bp[(wn + j * 16 + fr) * 64 + ((s * 32 + fq * 8) ^ rsw)];
#pragma unroll
    for (int i = 0; i < 8; i++) {
      s16x8 a0 = *(const s16x8*)&Ap[(wm + i * 16 + fr) * 64 + ((fq * 8) ^ rsw)];
      s16x8 a1 = *(const s16x8*)&Ap[(wm + i * 16 + fr) * 64 + ((32 + fq * 8) ^ rsw)];
#pragma unroll
      for (int j = 0; j < 4; j++) {
        acc[i][j] = mfma16(a0, bfr[j][0], acc[i][j]);
        acc[i][j] = mfma16(a1, bfr[j][1], acc[i][j]);
      }
    }
    __builtin_amdgcn_s_setprio(0);
    asm volatile("s_waitcnt lgkmcnt(0)" ::: "memory");  // ds_reads of buf[t&1] done (NOT vmcnt)
    __builtin_amdgcn_sched_barrier(0);
    __builtin_amdgcn_s_barrier();
  }

#pragma unroll
  for (int i = 0; i < 8; i++)
#pragma unroll
    for (int j = 0; j < 4; j++)
#pragma unroll
      for (int r = 0; r < 4; r++) {
        int row = bm + wm + i * 16 + fq * 4 + r;
        int col = bn + wn + j * 16 + fr;
        if (F32OUT) ((float*)Cout)[(size_t)row * N + col] = acc[i][j][r];
        else        ((u16*)Cout)[(size_t)row * N + col] = f2bf(acc[i][j][r]);
      }
}

// ================= 128x128 pipelined GEMM (for N=2304 out-proj: bigger grid) =================
// Same counted-vmcnt schedule at 128² tile, BK=32, 4 waves, vmcnt(4), 4-granule swizzle.
template <bool F32OUT>
__global__ __launch_bounds__(256) void gemm128(const u16* __restrict__ A, const u16* __restrict__ BT,
                                               void* __restrict__ Cout, int M, int N, int Kd) {
  __shared__ u16 As[2][128 * 32];
  __shared__ u16 Bs[2][128 * 32];
  int tid = threadIdx.x, lane = tid & 63, wave = tid >> 6;
  int nT = gridDim.x * gridDim.y;
  int bid = blockIdx.y * gridDim.x + blockIdx.x;
  int tile = (bid & 7) * (nT >> 3) + (bid >> 3);
  int bn = (tile % gridDim.x) * 128;
  int bm = (tile / gridDim.x) * 128;
  int wm = (wave >> 1) * 64, wn = (wave & 1) * 64;
  int fr = lane & 15, fq = lane >> 4;
  f32x4 acc[4][4];
#pragma unroll
  for (int i = 0; i < 4; i++)
#pragma unroll
    for (int j = 0; j < 4; j++) acc[i][j] = (f32x4){0.f, 0.f, 0.f, 0.f};

  int srow = tid >> 2, sslot = tid & 3;
  int scol = (sslot * 8) ^ ((srow & 3) << 3);
  const u16* Ab = A + (size_t)(bm + srow) * Kd + scol;
  const u16* Bb = BT + (size_t)(bn + srow) * Kd + scol;

  auto stage = [&](int buf, int k0) {
    async16(Ab + k0, (char*)&As[buf][0] + wave * 1024);
    async16(Ab + (size_t)64 * Kd + k0, (char*)&As[buf][0] + wave * 1024 + 4096);
    async16(Bb + k0, (char*)&Bs[buf][0] + wave * 1024);
    async16(Bb + (size_t)64 * Kd + k0, (char*)&Bs[buf][0] + wave * 1024 + 4096);
  };

  int NT = Kd >> 5;
  int rsw = (fr & 3) << 3;
  stage(0, 0);
  for (int t = 0; t < NT; ++t) {
    if (t + 1 < NT) {
      stage((t + 1) & 1, (t + 1) << 5);
      asm volatile("s_waitcnt vmcnt(4)" ::: "memory");
    } else {
      asm volatile("s_waitcnt vmcnt(0)" ::: "memory");
    }
    __builtin_amdgcn_sched_barrier(0);
    __builtin_amdgcn_s_barrier();
    __builtin_amdgcn_sched_barrier(0);
    const u16* Ap = &As[t & 1][0];
    const u16* Bp = &Bs[t & 1][0];
    __builtin_amdgcn_s_setprio(1);
    s16x8 af[4], bv[4];
#pragma unroll
    for (int i = 0; i < 4; i++) af[i] = *(const s16x8*)&Ap[(wm + i * 16 + fr) * 32 + ((fq * 8) ^ rsw)];
#pragma unroll
    for (int j = 0; j < 4; j++) bv[j] = *(const s16x8*)&Bp[(wn + j * 16 + fr) * 32 + ((fq * 8) ^ rsw)];
#pragma unroll
    for (int i = 0; i < 4; i++)
#pragma unroll
      for (int j = 0; j < 4; j++)
        acc[i][j] = mfma16(af[i], bv[j], acc[i][j]);
    __builtin_amdgcn_s_setprio(0);
    asm volatile("s_waitcnt lgkmcnt(0)" ::: "memory");
    __builtin_amdgcn_sched_barrier(0);
    __builtin_amdgcn_s_barrier();
  }
#pragma unroll
  for (int i = 0; i < 4; i++)
#pragma unroll
    for (int j = 0; j < 4; j++)
#pragma unroll
      for (int r = 0; r < 4; r++) {
        int row = bm + wm + i * 16 + fq * 4 + r;
        int col = bn + wn + j * 16 + fr;
        if (F32OUT) ((float*)Cout)[(size_t)row * N + col] = acc[i][j][r];
        else        ((u16*)Cout)[(size_t)row * N + col] = f2bf(acc[i][j][r]);
      }
}

// ---------------- RoPE in-place on strided buffer (+optional scale) ----------------
__global__ void rope_kernel(u16* __restrict__ buf, const int* __restrict__ pos_ids,
                            int nheads, int rowstride, int colofs, float scale) {
  int idx = blockIdx.x * blockDim.x + threadIdx.x;
  int d = idx & 127;
  int hn = idx >> 7;
  int h = hn % nheads;
  int row = hn / nheads;
  float pos = (float)pos_ids[row];
  double invf = exp((double)d * -0.07195578415606394); // -ln(10000)/128
  double f = (double)pos * invf;
  double sd, cd;
  sincos(f, &sd, &cd);
  float sv = (float)sd, cv = (float)cd;
  size_t base = (size_t)row * rowstride + colofs + (size_t)h * HD_ + d;
  float a = bf2f(buf[base]);
  float b = bf2f(buf[base + 128]);
  buf[base]       = f2bf((a * cv - b * sv) * scale);
  buf[base + 128] = f2bf((b * cv + a * sv) * scale);
}

// ---------------- flash attention, softcap, fixed-max softmax, swizzled LDS ----------
// QKV fused layout: row stride 4096; Q at col 0, K at col 2048 (V consumed via VT).
// grid: (32, 16). block 256 = 4 waves x 16 q-rows. KVBLK=32, double-buffered.
__global__ __launch_bounds__(256) void attn_kernel(const u16* __restrict__ QKV, const u16* __restrict__ VT,
                                                   const int* __restrict__ amask, u16* __restrict__ O) {
  __shared__ u16 Kl[2][32 * 256];   // [buf][key][hd]  16 KiB each, swizzled ^((key&7)<<3)
  __shared__ u16 Vl[2][256 * 32];   // [buf][hd][key]  16 KiB each, swizzled ^((hd&3)<<3)
  __shared__ u16 Pl[4][16 * 40];    // per-wave P, rows padded to 40 u16 (80B) -> conflict-free
  // complementary-qt pairing: co-resident blocks (y, y+8) get qt = x and 31-x
  int qt = (blockIdx.y & 8) ? (31 - (int)blockIdx.x) : (int)blockIdx.x;
  int bh = blockIdx.y;
  int b = bh >> 3, h = bh & 7, g = h >> 1;
  int tid = threadIdx.x, lane = tid & 63, wave = tid >> 6;
  int fr = lane & 15, fq = lane >> 4;
  int q0 = qt * 64;

  // Q fragments in registers (Q already scaled by 1/16 in rope)
  s16x8 qf[8];
  const u16* qb = QKV + (size_t)(b * S_ + q0 + wave * 16 + fr) * 4096 + h * 256 + fq * 8;
#pragma unroll
  for (int kk = 0; kk < 8; kk++) qf[kk] = *(const s16x8*)(qb + kk * 32);

  f32x4 zero4 = {0.f, 0.f, 0.f, 0.f};
  f32x4 oacc[16];
#pragma unroll
  for (int i = 0; i < 16; i++) oacc[i] = zero4;
  f32x4 lacc = zero4;                                     // softmax denominator via ones-MFMA
  s16x8 onesv;
#pragma unroll
  for (int i = 0; i < 8; i++) onesv[i] = (short)0x3F80;   // bf16 1.0

  const u16* Kbase = QKV + (size_t)b * S_ * 4096 + 2048 + g * 256;
  const u16* Vbase = VT + (size_t)(b * 4 + g) * 256 * S_;

  // staging: per wave, K rows wave*8..+7 (512B each), V rows wave*64..+63 (64B each)
  auto stage = [&](int buf, int k0) {
#pragma unroll
    for (int it = 0; it < 4; ++it) {
      int rl = it * 2 + (lane >> 5);                         // K row within tile's wave slice
      int kce = ((lane & 31) * 8) ^ ((rl & 7) << 3);         // pre-swizzled source col
      async16(Kbase + (size_t)(k0 + wave * 8 + rl) * 4096 + kce,
              (char*)&Kl[buf][0] + wave * 4096 + it * 1024);
      int dl = wave * 64 + it * 16 + (lane >> 2);            // V row (hd)
      int vce = ((lane & 3) * 8) ^ (((lane >> 2) & 3) << 3);
      async16(Vbase + (size_t)dl * 2048 + k0 + vce,
              (char*)&Vl[buf][0] + wave * 4096 + it * 1024);
    }
  };

  int nt = 2 * qt + 2;                                        // 32-key tiles
  stage(0, 0);
  __syncthreads();                                            // drains vmcnt
  int buf = 0;
  int ksw = (fr & 7) << 3;                                    // K read swizzle
  int vsw = (fr & 3) << 3;                                    // V read swizzle
  for (int t = 0; t < nt; ++t) {
    int k0 = t * 32;
    if (t + 1 < nt) stage(buf ^ 1, k0 + 32);                  // issue-ahead into other buffer
    int am0 = amask[b * S_ + k0 + fr];
    int am1 = amask[b * S_ + k0 + 16 + fr];

    f32x4 s0 = zero4, s1 = zero4;
#pragma unroll
    for (int kk = 0; kk < 8; kk++) {
      s16x8 b0 = *(const s16x8*)&Kl[buf][fr * 256 + ((kk * 32 + fq * 8) ^ ksw)];
      s16x8 b1 = *(const s16x8*)&Kl[buf][(16 + fr) * 256 + ((kk * 32 + fq * 8) ^ ksw)];
      s0 = mfma16(qf[kk], b0, s0);
      s1 = mfma16(qf[kk], b1, s1);
    }

    bool needmask = (t >= nt - 2);
#pragma unroll
    for (int r = 0; r < 4; r++) {
      int qrow = fq * 4 + r;
      int qg = q0 + wave * 16 + qrow;
      // p = exp(50*tanh(s/50) - 50) = exp(-100/(exp(0.04*s)+1))   [fixed max = 50]
      float e20 = __expf(s0[r] * 0.04f);
      float e21 = __expf(s1[r] * 0.04f);
      float p0 = __expf(-100.f / (e20 + 1.f));
      float p1 = __expf(-100.f / (e21 + 1.f));
      bool ok0 = (am0 > 0) && (!needmask || (k0 + fr) <= qg);
      bool ok1 = (am1 > 0) && (!needmask || (k0 + 16 + fr) <= qg);
      p0 = ok0 ? p0 : 0.f;
      p1 = ok1 ? p1 : 0.f;
      Pl[wave][qrow * 40 + fr] = f2bf(p0);
      Pl[wave][qrow * 40 + 16 + fr] = f2bf(p1);
    }
    asm volatile("s_waitcnt lgkmcnt(0)" ::: "memory");
    __builtin_amdgcn_sched_barrier(0);

    s16x8 pf = *(const s16x8*)&Pl[wave][fr * 40 + fq * 8];
    lacc = mfma16(pf, onesv, lacc);                           // row-sum of P (all cols equal)
#pragma unroll
    for (int df = 0; df < 16; df++) {
      s16x8 vv = *(const s16x8*)&Vl[buf][(df * 16 + fr) * 32 + ((fq * 8) ^ vsw)];
      oacc[df] = mfma16(pf, vv, oacc[df]);
    }
    __syncthreads();                                          // drains next-tile loads too
    buf ^= 1;
  }

  float rinv[4];
#pragma unroll
  for (int r = 0; r < 4; r++) rinv[r] = 1.0f / lacc[r];
#pragma unroll
  for (int df = 0; df < 16; df++) {
#pragma unroll
    for (int r = 0; r < 4; r++) {
      float ov = oacc[df][r] * rinv[r];
      O[(size_t)(b * S_ + q0 + wave * 16 + fq * 4 + r) * 2048 + h * 256 + df * 16 + fr] = f2bf(ov);
    }
  }
}

extern "C" void kernel_launch(void* const* d_in, const int* in_sizes, int n_in,
                              void* d_out, int out_size, void* d_ws, size_t ws_size,
                              hipStream_t stream) {
  const float* X   = (const float*)d_in[0];   // [B,S,H] fp32
  const int* amask = (const int*)d_in[1];
  const int* pos   = (const int*)d_in[2];
  const float* Wq  = (const float*)d_in[3];   // [H, NH*HD] fp32
  const float* Wk  = (const float*)d_in[4];
  const float* Wv  = (const float*)d_in[5];
  const float* Wo  = (const float*)d_in[6];
  float* out = (float*)d_out;                 // [B,S,H] fp32

  char* ws = (char*)d_ws;
  size_t off = 0;
  auto alloc = [&](size_t elems) {
    u16* p = (u16*)(ws + off);
    off += ((elems * 2 + 255) & ~(size_t)255);
    return p;
  };
  u16* Xb   = alloc((size_t)4096 * 2304);
  u16* WqT  = alloc((size_t)2048 * 2304);   // WqT/WkT/WvT contiguous => fused [4096][2304] B^T
  u16* WkT  = alloc((size_t)1024 * 2304);
  u16* WvT  = alloc((size_t)1024 * 2304);
  u16* WoT  = alloc((size_t)2304 * 2048);
  u16* QKV  = alloc((size_t)4096 * 4096);   // fused projection output [4096][Q|K|V]
  u16* VTb  = alloc((size_t)4096 * 1024);
  u16* AO   = alloc((size_t)4096 * 2048);
  if (off > ws_size) return;  // insufficient workspace -> leave zeros (loud failure)

  // hidden_states fp32 -> bf16
  {
    size_t n = (size_t)4096 * 2304;
    f32_to_bf16<<<(unsigned)((n / 4 + 255) / 256), 256, 0, stream>>>(X, Xb, n);
  }

  dim3 tb(32, 8);
  // weight transposes (fp32 -> bf16): W[K][N] -> WT[N][K]
  transpose_f32_bf16<<<dim3(2048 / 32, 2304 / 32), tb, 0, stream>>>(Wq, WqT, 2304, 2048);
  transpose_f32_bf16<<<dim3(1024 / 32, 2304 / 32), tb, 0, stream>>>(Wk, WkT, 2304, 1024);
  transpose_f32_bf16<<<dim3(1024 / 32, 2304 / 32), tb, 0, stream>>>(Wv, WvT, 2304, 1024);
  transpose_f32_bf16<<<dim3(2304 / 32, 2048 / 32), tb, 0, stream>>>(Wo, WoT, 2048, 2304);

  // fused QKV projection: [4096][2304] x [4096][2304]^T -> [4096][4096] bf16 (256² pipelined)
  gemm256<false><<<dim3(4096 / 256, 4096 / 256), 512, 0, stream>>>(Xb, WqT, QKV, 4096, 4096, 2304);

  // RoPE in-place on fused buffer (scale 1/16 folded into Q)
  rope_kernel<<<(4096 * 8 * 128) / 256, 256, 0, stream>>>(QKV, pos, 8, 4096, 0, 1.0f / 16.0f);
  rope_kernel<<<(4096 * 4 * 128) / 256, 256, 0, stream>>>(QKV, pos, 4, 4096, 2048, 1.0f);

  // V (QKV cols 3072..4095) -> VT[b][kv][d][s]
  transpose_bf16_s<<<dim3(1024 / 32, 2048 / 32, 2), tb, 0, stream>>>(
      QKV + 3072, VTb, 2048, 1024, 4096, (size_t)2048 * 4096, (size_t)1024 * 2048);

  // attention (bf16 out)
  attn_kernel<<<dim3(32, 16), 256, 0, stream>>>(QKV, VTb, amask, AO);

  // output projection -> fp32 d_out (128² pipelined, grid 18x32=576)
  gemm128<true><<<dim3(2304 / 128, 4096 / 128), 256, 0, stream>>>(AO, WoT, out, 4096, 2304, 2048);
}